// Round 11
// baseline (2360.526 us; speedup 1.0000x reference)
//
#include <hip/hip_runtime.h>
#include <math.h>

// LSTM: B=128, T=256, D=256, H=1024, C=10
// Round 12: B-dedup, conservatively. R11 (1951us) kept; only change vs R11:
//   block covers 32 batch rows (two independent 16-row A-tiles, each in the
//   PROVEN R1-linear fragment layout + R11 swzb swizzle), so each wave's one
//   B stream feeds 4 MFMAs instead of 2.
//   Why: step ~7.2us is dominated by B traffic through L2 (each XCD pulls
//   10.5 MB/step; 8 by-blocks per n-tile re-read the same 327KB) plus
//   exposed L2 latency at 2 B-loads per 2 MFMAs. This halves per-XCD B
//   traffic (5.25 MB/step) and doubles MFMA work per B-load.
//   R10 tried this and regressed because it ALSO changed the A layout
//   (staging swizzle left 4-way conflicts), halved the n-tile, and lacked
//   R11's fixes. Here every proven element is bit-identical: A layout,
//   staging geometry (run twice), swzb, c-prefetch, fast-math, epilogue
//   C/D mapping, 2-units/thread cell update (R1's rep=2).
//   Also: single-phase K-half combine (kh0 writes acc+bias to pLds0, kh1
//   raw to pLds1, ONE barrier, cell sums) removes a barrier + add pass.
//   PFB 8 (covers ~280cyc L2 latency), PFA 4 per stream.
//   LDS: 2x40KB A + 2x16.9KB pLds = 113KB. ~165 VGPR, 2 waves/SIMD.
//   Grid (32,4) = 128 blocks; bx%8 spans all 8 XCDs (16 blocks each).
// Workspace layout (28,311,552 B total):
//   [0)          Wpack  bf16  10,485,760 B
//   [10485760)   xT     bf16  16,777,216 B   ([T][B][D], x transposed+cast)
//   [27262976)   h0     bf16     262,144 B
//   [27525120)   h1     bf16     262,144 B
//   [27787264)   c      fp32     524,288 B

#define BB 128
#define TT 256
#define DD 256
#define HH 1024
#define NKT 40   // 1280 / 32 k-tiles
#define KHT 20   // k-tiles per K-half wave
#define PFA 4    // A-fragment prefetch depth (per row-tile stream)
#define PFB 8    // B-fragment prefetch depth

typedef __bf16 bf16x8 __attribute__((ext_vector_type(8)));
typedef float  f32x4  __attribute__((ext_vector_type(4)));
typedef unsigned short u16;
typedef u16 u16x8 __attribute__((ext_vector_type(8)));

__device__ __forceinline__ u16 f2bf(float f){
  unsigned u = __builtin_bit_cast(unsigned, f);
  u += 0x7fffu + ((u >> 16) & 1u);            // round-to-nearest-even
  return (u16)(u >> 16);
}
__device__ __forceinline__ float bf2f(u16 b){
  unsigned u = ((unsigned)b) << 16;
  return __builtin_bit_cast(float, u);
}
__device__ __forceinline__ float sigm(float x){
  return 1.f / (1.f + __expf(-x));            // R3/R4/R11-proven numerics
}
__device__ __forceinline__ float tanh_fast(float x){
  return 2.f / (1.f + __expf(-2.f * x)) - 1.f;
}
// As slot bits (per 16-row tile): m=[0:3], q=[4:5], kt=[6:11]. R11-proven
// involution: staging wave's 8 consecutive lanes -> 8 distinct bank groups;
// K-loop reads stay linear in lane (slot = kt*64 + lane before swizzle).
__device__ __forceinline__ int swzb(int slot){
  return slot ^ ((slot >> 6) & 7) ^ (((slot >> 4) & 3) << 1);
}

// ---- pack weights into MFMA B-fragment order -------------------------------
// Wpack[ct][kt][lane][j]: ct in [0,256) covers gate-cols [ct*16, ct*16+16)
// (col = gate*1024 + n); element = W[k = kt*32 + (lane>>4)*8 + j][col = ct*16 + (lane&15)]
__global__ void prep_wpack(const float* __restrict__ Wfx, const float* __restrict__ Wix,
                           const float* __restrict__ Wgx, const float* __restrict__ Wox,
                           const float* __restrict__ Wfh, const float* __restrict__ Wih,
                           const float* __restrict__ Wgh, const float* __restrict__ Woh,
                           u16* __restrict__ Wpack){
  int id = blockIdx.x * 256 + threadIdx.x;    // [0, 655360)
  int lane = id & 63;
  int kt = (id >> 6) % NKT;
  int ct = id / (64 * NKT);
  int col = ct * 16 + (lane & 15);
  int g = col >> 10, n = col & 1023;
  int kbase = kt * 32 + (lane >> 4) * 8;
  const float* Wx = (g==0) ? Wfx : (g==1) ? Wix : (g==2) ? Wgx : Wox;
  const float* Wh = (g==0) ? Wfh : (g==1) ? Wih : (g==2) ? Wgh : Woh;
  u16x8 v;
  #pragma unroll
  for (int j = 0; j < 8; ++j){
    int k = kbase + j;
    float f = (k < DD) ? Wx[k * HH + n] : Wh[(k - DD) * HH + n];
    v[j] = f2bf(f);
  }
  *(u16x8*)(Wpack + (size_t)id * 8) = v;      // dst index == id (by construction)
}

// ---- transpose+cast x: xT[t][b][d] = bf16(x[b][t][d]) ----------------------
__global__ void prep_xT(const float* __restrict__ x, u16* __restrict__ xT){
  int id = blockIdx.x * 256 + threadIdx.x;    // [0, 1048576), 8 elems each
  int t = id >> 12;
  int b = (id >> 5) & 127;
  int d0 = (id & 31) * 8;
  const float* src = x + ((size_t)b * TT + t) * DD + d0;
  u16x8 v;
  #pragma unroll
  for (int j = 0; j < 8; ++j) v[j] = f2bf(src[j]);
  *(u16x8*)(xT + (size_t)id * 8) = v;
}

// ---- one LSTM time step: GEMM (bf16 MFMA) + gate activations + state update
// Block: 32 rows x 32 cols x 4 gates. Waves: g = w&3, kh = w>>2 (R1 split).
// Each wave: one B stream (2 col-tiles, 20 kt), TWO 16-row A tiles -> 80 MFMA.
__global__ __launch_bounds__(512) void lstm_step3(
    const u16* __restrict__ xTt,   // [128][256] bf16 (t-slice of xT)
    const u16* __restrict__ Wpack,
    const u16* __restrict__ hin,   // [128][1024] bf16
    u16* __restrict__ hout,        // [128][1024] bf16
    float* __restrict__ cbuf,      // [128][1024] fp32
    const float* __restrict__ bfv, const float* __restrict__ biv,
    const float* __restrict__ bgv, const float* __restrict__ bov){
  __shared__ u16x8 AsLo[NKT * 64];   // 40 KB: rows m0..m0+15, R1 layout+swzb
  __shared__ u16x8 AsHi[NKT * 64];   // 40 KB: rows m0+16..m0+31
  __shared__ float pLds0[32][132];   // kh=0 partials (+bias), 16.9 KB
  __shared__ float pLds1[32][132];   // kh=1 partials, 16.9 KB
  const int tid = threadIdx.x;
  const int n0 = blockIdx.x * 32;    // hidden-col tile; bx%8 = XCD
  const int m0 = blockIdx.y * 32;    // batch-row tile

  // cell ownership fixed by tid (2 units, R1's rep=2) -> prefetch c now
  const int crow0 = tid >> 5,        cnn0 = tid & 31;
  const int crow1 = (tid + 512) >> 5, cnn1 = cnn0;
  const int gi0 = (m0 + crow0) * HH + n0 + cnn0;
  const int gi1 = (m0 + crow1) * HH + n0 + cnn1;
  const float cprev0 = cbuf[gi0];
  const float cprev1 = cbuf[gi1];

  const int w = tid >> 6, lane = tid & 63, cr = lane & 15, q4 = lane >> 4;
  const int g  = w & 3;              // gate
  const int kh = w >> 2;             // K-half: kt in [kh*20, kh*20+20)
  const int ktBeg = kh * KHT;

  // B fragment streams (identical to R1/R11): ct0 = g*64 + bx*2, 2 col-tiles.
  const size_t ct0 = (size_t)(g * 64 + blockIdx.x * 2);
  const u16x8* Wp = (const u16x8*)Wpack;
  const u16x8* wq0 = Wp + ct0 * NKT * 64 + lane;
  const u16x8* wq1 = wq0 + NKT * 64;

  u16x8 b0P[PFB], b1P[PFB];
  #pragma unroll
  for (int i = 0; i < PFB; ++i){
    b0P[i] = wq0[(size_t)(ktBeg + i) * 64];
    b1P[i] = wq1[(size_t)(ktBeg + i) * 64];
  }

  // Stage two 16-row A tiles, each with the R11-proven pattern (5 iters x 512).
  // chunk ch -> row m = ch/160, k0 = (ch%160)*8 ; slot = kt*64 + 16*q + m
  #pragma unroll
  for (int it = 0; it < 5; ++it){
    int ch = tid + it * 512;
    int m = ch / 160;
    int k0 = (ch - m * 160) * 8;
    const u16* src = (k0 < DD) ? (xTt + (m0 + m) * DD + k0)
                               : (hin + (m0 + m) * HH + (k0 - DD));
    u16x8 val = *(const u16x8*)src;
    int kt = k0 >> 5, q = (k0 >> 3) & 3;
    AsLo[swzb(kt * 64 + 16 * q + m)] = val;
  }
  #pragma unroll
  for (int it = 0; it < 5; ++it){
    int ch = tid + it * 512;
    int m = ch / 160;
    int k0 = (ch - m * 160) * 8;
    const u16* src = (k0 < DD) ? (xTt + (m0 + 16 + m) * DD + k0)
                               : (hin + (m0 + 16 + m) * HH + (k0 - DD));
    u16x8 val = *(const u16x8*)src;
    int kt = k0 >> 5, q = (k0 >> 3) & 3;
    AsHi[swzb(kt * 64 + 16 * q + m)] = val;
  }
  __syncthreads();

  u16x8 aLoP[PFA], aHiP[PFA];
  #pragma unroll
  for (int i = 0; i < PFA; ++i){
    aLoP[i] = AsLo[swzb((ktBeg + i) * 64 + lane)];
    aHiP[i] = AsHi[swzb((ktBeg + i) * 64 + lane)];
  }

  f32x4 aL0 = {0.f,0.f,0.f,0.f}, aL1 = {0.f,0.f,0.f,0.f};
  f32x4 aH0 = {0.f,0.f,0.f,0.f}, aH1 = {0.f,0.f,0.f,0.f};
  #pragma unroll
  for (int kt = 0; kt < KHT; ++kt){
    u16x8 alo = aLoP[kt & (PFA - 1)], ahi = aHiP[kt & (PFA - 1)];
    u16x8 b0  = b0P[kt & (PFB - 1)],  b1  = b1P[kt & (PFB - 1)];
    if (kt + PFA < KHT){
      aLoP[kt & (PFA - 1)] = AsLo[swzb((ktBeg + kt + PFA) * 64 + lane)];
      aHiP[kt & (PFA - 1)] = AsHi[swzb((ktBeg + kt + PFA) * 64 + lane)];
    }
    if (kt + PFB < KHT){
      b0P[kt & (PFB - 1)] = wq0[(size_t)(ktBeg + kt + PFB) * 64];
      b1P[kt & (PFB - 1)] = wq1[(size_t)(ktBeg + kt + PFB) * 64];
    }
    aL0 = __builtin_amdgcn_mfma_f32_16x16x32_bf16(__builtin_bit_cast(bf16x8, alo),
            __builtin_bit_cast(bf16x8, b0), aL0, 0, 0, 0);
    aL1 = __builtin_amdgcn_mfma_f32_16x16x32_bf16(__builtin_bit_cast(bf16x8, alo),
            __builtin_bit_cast(bf16x8, b1), aL1, 0, 0, 0);
    aH0 = __builtin_amdgcn_mfma_f32_16x16x32_bf16(__builtin_bit_cast(bf16x8, ahi),
            __builtin_bit_cast(bf16x8, b0), aH0, 0, 0, 0);
    aH1 = __builtin_amdgcn_mfma_f32_16x16x32_bf16(__builtin_bit_cast(bf16x8, ahi),
            __builtin_bit_cast(bf16x8, b1), aH1, 0, 0, 0);
  }

  // single-phase combine: kh0 writes acc+bias to pLds0, kh1 raw to pLds1.
  // C/D layout (R1-proven): col = cr, local row = q4*4+r; Hi tile rows +16.
  if (!kh){
    const float* bptr = (g==0) ? bfv : (g==1) ? biv : (g==2) ? bgv : bov;
    const float bias0 = bptr[n0 + cr], bias1 = bptr[n0 + 16 + cr];
    #pragma unroll
    for (int r = 0; r < 4; ++r){
      pLds0[q4 * 4 + r][g * 32 + cr]           = aL0[r] + bias0;
      pLds0[q4 * 4 + r][g * 32 + 16 + cr]      = aL1[r] + bias1;
      pLds0[16 + q4 * 4 + r][g * 32 + cr]      = aH0[r] + bias0;
      pLds0[16 + q4 * 4 + r][g * 32 + 16 + cr] = aH1[r] + bias1;
    }
  } else {
    #pragma unroll
    for (int r = 0; r < 4; ++r){
      pLds1[q4 * 4 + r][g * 32 + cr]           = aL0[r];
      pLds1[q4 * 4 + r][g * 32 + 16 + cr]      = aL1[r];
      pLds1[16 + q4 * 4 + r][g * 32 + cr]      = aH0[r];
      pLds1[16 + q4 * 4 + r][g * 32 + 16 + cr] = aH1[r];
    }
  }
  __syncthreads();

  // fused LSTM cell update: 1024 units, 2 per thread (R1's rep=2 mapping)
  {
    float fp = pLds0[crow0][cnn0]      + pLds1[crow0][cnn0];
    float ip = pLds0[crow0][32 + cnn0] + pLds1[crow0][32 + cnn0];
    float gp = pLds0[crow0][64 + cnn0] + pLds1[crow0][64 + cnn0];
    float op = pLds0[crow0][96 + cnn0] + pLds1[crow0][96 + cnn0];
    float cn = tanh_fast(gp) * sigm(ip) + cprev0 * sigm(fp);
    cbuf[gi0] = cn;
    hout[gi0] = f2bf(tanh_fast(cn) * sigm(op));
  }
  {
    float fp = pLds0[crow1][cnn1]      + pLds1[crow1][cnn1];
    float ip = pLds0[crow1][32 + cnn1] + pLds1[crow1][32 + cnn1];
    float gp = pLds0[crow1][64 + cnn1] + pLds1[crow1][64 + cnn1];
    float op = pLds0[crow1][96 + cnn1] + pLds1[crow1][96 + cnn1];
    float cn = tanh_fast(gp) * sigm(ip) + cprev1 * sigm(fp);
    cbuf[gi1] = cn;
    hout[gi1] = f2bf(tanh_fast(cn) * sigm(op));
  }
}

// ---- out[b][c] = h_T[b] . Wph[:,c] + bp[c] ---------------------------------
__global__ void final_proj(const u16* __restrict__ h, const float* __restrict__ Wph,
                           const float* __restrict__ bp, float* __restrict__ out){
  __shared__ float red[10][256];
  int b = blockIdx.x, tid = threadIdx.x;
  float p[10];
  #pragma unroll
  for (int c = 0; c < 10; ++c) p[c] = 0.f;
  for (int k = tid; k < HH; k += 256){
    float hv = bf2f(h[b * HH + k]);
    const float* wr = Wph + (size_t)k * 10;
    #pragma unroll
    for (int c = 0; c < 10; ++c) p[c] += hv * wr[c];
  }
  #pragma unroll
  for (int c = 0; c < 10; ++c) red[c][tid] = p[c];
  __syncthreads();
  for (int s = 128; s > 0; s >>= 1){
    if (tid < s){
      #pragma unroll
      for (int c = 0; c < 10; ++c) red[c][tid] += red[c][tid + s];
    }
    __syncthreads();
  }
  if (tid < 10) out[b * 10 + tid] = red[tid][0] + bp[tid];
}

extern "C" void kernel_launch(void* const* d_in, const int* in_sizes, int n_in,
                              void* d_out, int out_size, void* d_ws, size_t ws_size,
                              hipStream_t stream){
  (void)in_sizes; (void)n_in; (void)out_size; (void)ws_size;
  const float* x   = (const float*)d_in[0];
  const float* Wfx = (const float*)d_in[1];
  const float* Wix = (const float*)d_in[2];
  const float* Wgx = (const float*)d_in[3];
  const float* Wox = (const float*)d_in[4];
  const float* Wfh = (const float*)d_in[5];
  const float* Wih = (const float*)d_in[6];
  const float* Wgh = (const float*)d_in[7];
  const float* Woh = (const float*)d_in[8];
  const float* bfv = (const float*)d_in[9];
  const float* biv = (const float*)d_in[10];
  const float* bgv = (const float*)d_in[11];
  const float* bov = (const float*)d_in[12];
  const float* Wph = (const float*)d_in[13];
  const float* bp  = (const float*)d_in[14];

  char* ws = (char*)d_ws;
  u16*  Wpack = (u16*)ws;                    // 10,485,760 B
  u16*  xT    = (u16*)(ws + 10485760);       // 16,777,216 B
  u16*  h0    = (u16*)(ws + 27262976);       //    262,144 B
  u16*  h1    = (u16*)(ws + 27525120);       //    262,144 B
  float* cb   = (float*)(ws + 27787264);     //    524,288 B

  prep_wpack<<<2560, 256, 0, stream>>>(Wfx, Wix, Wgx, Wox, Wfh, Wih, Wgh, Woh, Wpack);
  prep_xT<<<4096, 256, 0, stream>>>(x, xT);
  hipMemsetAsync(h0, 0, 262144, stream);
  hipMemsetAsync(cb, 0, 524288, stream);

  for (int t = 0; t < TT; ++t){
    const u16* hin  = (t & 1) ? h1 : h0;
    u16*       hout = (t & 1) ? h0 : h1;
    lstm_step3<<<dim3(32, 4), 512, 0, stream>>>(xT + (size_t)t * BB * DD, Wpack,
                                                hin, hout, cb, bfv, biv, bgv, bov);
  }
  // t=255 (odd) wrote h0 -> final hidden state lives in h0
  final_proj<<<128, 256, 0, stream>>>(h0, Wph, bp, (float*)d_out);
}

// Round 12
// 1905.656 us; speedup vs baseline: 1.2387x; 1.2387x over previous
//
#include <hip/hip_runtime.h>
#include <math.h>

// LSTM: B=128, T=256, D=256, H=1024, C=10
// Round 13: R11 (proven best, 1951us) + single-phase combine only.
//   R12 post-mortem: grid (32,4)=128 blocks left HALF the CUs idle (my
//   error) while doubling each wave's serial MFMA chain -> 2360us. The
//   B-dedup thesis is dead (R10: 2150, R12: 2360; both regress).
//   Meta-lesson across R10-R12: in-kernel memory restructures barely move
//   this kernel. R11's bank-conflict fix (1.47e8 measured conflict cycles,
//   predicted -0.9us/step) delivered only -0.13us/step: conflicts were real
//   but off the critical path. The step is a sum of small latency terms
//   (launch ~2us, L2 round-trips after per-launch acquire-invalidate,
//   20-iter MFMA pipeline, epilogue barriers). Persistence is closed
//   (remat x5, coop-under-capture fails, barrier >= launch cost).
//   Only change vs R11: single-phase K-half combine. kh0 waves write
//   acc+bias to pLds0, kh1 raw acc to pLds1, ONE barrier (was two), cell
//   update sums both. Removes one syncthreads + one LDS RMW pass per step.
//   Staging loop cleaned to plain 5 iters (identical addresses to R11).
// Workspace layout (28,311,552 B total):
//   [0)          Wpack  bf16  10,485,760 B
//   [10485760)   xT     bf16  16,777,216 B   ([T][B][D], x transposed+cast)
//   [27262976)   h0     bf16     262,144 B
//   [27525120)   h1     bf16     262,144 B
//   [27787264)   c      fp32     524,288 B

#define BB 128
#define TT 256
#define DD 256
#define HH 1024
#define NKT 40   // 1280 / 32 k-tiles
#define KHT 20   // k-tiles per K-half wave
#define PFA 4    // A-fragment prefetch depth
#define PFB 5    // B-fragment prefetch depth

typedef __bf16 bf16x8 __attribute__((ext_vector_type(8)));
typedef float  f32x4  __attribute__((ext_vector_type(4)));
typedef unsigned short u16;
typedef u16 u16x8 __attribute__((ext_vector_type(8)));

__device__ __forceinline__ u16 f2bf(float f){
  unsigned u = __builtin_bit_cast(unsigned, f);
  u += 0x7fffu + ((u >> 16) & 1u);            // round-to-nearest-even
  return (u16)(u >> 16);
}
__device__ __forceinline__ float bf2f(u16 b){
  unsigned u = ((unsigned)b) << 16;
  return __builtin_bit_cast(float, u);
}
__device__ __forceinline__ float sigm(float x){
  return 1.f / (1.f + __expf(-x));            // R3/R4/R11-proven numerics
}
__device__ __forceinline__ float tanh_fast(float x){
  return 2.f / (1.f + __expf(-2.f * x)) - 1.f;
}
// As4 slot bits: m=[0:3], q=[4:5], kt=[6:11]. R11-proven involution:
// staging wave's 8 consecutive lanes -> 8 distinct bank groups; K-loop
// reads stay spread (slot = kt*64 + lane before swizzle).
__device__ __forceinline__ int swzb(int slot){
  return slot ^ ((slot >> 6) & 7) ^ (((slot >> 4) & 3) << 1);
}

// ---- pack weights into MFMA B-fragment order -------------------------------
// Wpack[ct][kt][lane][j]: ct in [0,256) covers gate-cols [ct*16, ct*16+16)
// (col = gate*1024 + n); element = W[k = kt*32 + (lane>>4)*8 + j][col = ct*16 + (lane&15)]
__global__ void prep_wpack(const float* __restrict__ Wfx, const float* __restrict__ Wix,
                           const float* __restrict__ Wgx, const float* __restrict__ Wox,
                           const float* __restrict__ Wfh, const float* __restrict__ Wih,
                           const float* __restrict__ Wgh, const float* __restrict__ Woh,
                           u16* __restrict__ Wpack){
  int id = blockIdx.x * 256 + threadIdx.x;    // [0, 655360)
  int lane = id & 63;
  int kt = (id >> 6) % NKT;
  int ct = id / (64 * NKT);
  int col = ct * 16 + (lane & 15);
  int g = col >> 10, n = col & 1023;
  int kbase = kt * 32 + (lane >> 4) * 8;
  const float* Wx = (g==0) ? Wfx : (g==1) ? Wix : (g==2) ? Wgx : Wox;
  const float* Wh = (g==0) ? Wfh : (g==1) ? Wih : (g==2) ? Wgh : Woh;
  u16x8 v;
  #pragma unroll
  for (int j = 0; j < 8; ++j){
    int k = kbase + j;
    float f = (k < DD) ? Wx[k * HH + n] : Wh[(k - DD) * HH + n];
    v[j] = f2bf(f);
  }
  *(u16x8*)(Wpack + (size_t)id * 8) = v;      // dst index == id (by construction)
}

// ---- transpose+cast x: xT[t][b][d] = bf16(x[b][t][d]) ----------------------
__global__ void prep_xT(const float* __restrict__ x, u16* __restrict__ xT){
  int id = blockIdx.x * 256 + threadIdx.x;    // [0, 1048576), 8 elems each
  int t = id >> 12;
  int b = (id >> 5) & 127;
  int d0 = (id & 31) * 8;
  const float* src = x + ((size_t)b * TT + t) * DD + d0;
  u16x8 v;
  #pragma unroll
  for (int j = 0; j < 8; ++j) v[j] = f2bf(src[j]);
  *(u16x8*)(xT + (size_t)id * 8) = v;
}

// ---- one LSTM time step: GEMM (bf16 MFMA) + gate activations + state update
__global__ __launch_bounds__(512) void lstm_step(
    const u16* __restrict__ xTt,   // [128][256] bf16 (t-slice of xT)
    const u16* __restrict__ Wpack,
    const u16* __restrict__ hin,   // [128][1024] bf16
    u16* __restrict__ hout,        // [128][1024] bf16
    float* __restrict__ cbuf,      // [128][1024] fp32
    const float* __restrict__ bfv, const float* __restrict__ biv,
    const float* __restrict__ bgv, const float* __restrict__ bov){
  __shared__ u16x8 As4[NKT * 64];  // 40 KB: A tile in fragment order (swizzled)
  __shared__ float pLds0[16][132]; // kh=0 partials (+bias), 8.25 KB
  __shared__ float pLds1[16][132]; // kh=1 partials, 8.25 KB
  const int tid = threadIdx.x;
  const int n0 = blockIdx.x * 32;  // hidden-unit tile
  const int m0 = blockIdx.y * 16;  // batch-row tile

  // cell-update ownership fixed by tid -> prefetch c-state NOW (hides ~500cyc)
  const int crow = tid >> 5, cnn = tid & 31;
  const int gi = (m0 + crow) * HH + n0 + cnn;
  const float cprev = cbuf[gi];

  const int w = tid >> 6, lane = tid & 63, cr = lane & 15, q4 = lane >> 4;
  const int g  = w & 3;            // gate
  const int kh = w >> 2;           // K-half: kt in [kh*20, kh*20+20)
  const int ktBeg = kh * KHT;

  // B fragment pointers (global, L2-resident pack); prologue loads issued
  // BEFORE staging so weight latency overlaps the A-staging phase.
  const size_t ct0 = (size_t)(g * 64 + blockIdx.x * 2);  // 2 col-tiles of gate g
  const u16x8* Wp = (const u16x8*)Wpack;
  const u16x8* wq0 = Wp + ct0 * NKT * 64 + lane;
  const u16x8* wq1 = wq0 + NKT * 64;

  u16x8 aP[PFA], b0P[PFB], b1P[PFB];
  #pragma unroll
  for (int i = 0; i < PFB; ++i){
    b0P[i] = wq0[(size_t)(ktBeg + i) * 64];
    b1P[i] = wq1[(size_t)(ktBeg + i) * 64];
  }

  // Stage A = [x_t rows | h rows] into LDS in MFMA A-fragment order, swizzled.
  // chunk ch -> row m = ch/160, k0 = (ch%160)*8 ; slot = kt*64 + 16*q + m
  #pragma unroll
  for (int it = 0; it < 5; ++it){
    int ch = tid + it * 512;
    int m = ch / 160;
    int k0 = (ch - m * 160) * 8;
    const u16* src = (k0 < DD) ? (xTt + (m0 + m) * DD + k0)
                               : (hin + (m0 + m) * HH + (k0 - DD));
    u16x8 val = *(const u16x8*)src;
    int kt = k0 >> 5, q = (k0 >> 3) & 3;
    As4[swzb(kt * 64 + 16 * q + m)] = val;
  }
  __syncthreads();

  #pragma unroll
  for (int i = 0; i < PFA; ++i) aP[i] = As4[swzb((ktBeg + i) * 64 + lane)];

  f32x4 acc0 = {0.f, 0.f, 0.f, 0.f}, acc1 = {0.f, 0.f, 0.f, 0.f};
  #pragma unroll
  for (int kt = 0; kt < KHT; ++kt){
    u16x8 ac = aP[kt % PFA], b0 = b0P[kt % PFB], b1 = b1P[kt % PFB];
    if (kt + PFA < KHT)
      aP[kt % PFA] = As4[swzb((ktBeg + kt + PFA) * 64 + lane)];
    if (kt + PFB < KHT){
      b0P[kt % PFB] = wq0[(size_t)(ktBeg + kt + PFB) * 64];
      b1P[kt % PFB] = wq1[(size_t)(ktBeg + kt + PFB) * 64];
    }
    acc0 = __builtin_amdgcn_mfma_f32_16x16x32_bf16(__builtin_bit_cast(bf16x8, ac),
             __builtin_bit_cast(bf16x8, b0), acc0, 0, 0, 0);
    acc1 = __builtin_amdgcn_mfma_f32_16x16x32_bf16(__builtin_bit_cast(bf16x8, ac),
             __builtin_bit_cast(bf16x8, b1), acc1, 0, 0, 0);
  }

  // single-phase combine (C/D layout: col=lane&15, row=q4*4+r):
  // kh=0 writes acc+bias -> pLds0, kh=1 writes raw acc -> pLds1, ONE barrier.
  if (!kh){
    const float* bptr = (g==0) ? bfv : (g==1) ? biv : (g==2) ? bgv : bov;
    const float bias0 = bptr[n0 + cr], bias1 = bptr[n0 + 16 + cr];
    #pragma unroll
    for (int r = 0; r < 4; ++r){
      pLds0[q4 * 4 + r][g * 32 + cr]      = acc0[r] + bias0;
      pLds0[q4 * 4 + r][g * 32 + 16 + cr] = acc1[r] + bias1;
    }
  } else {
    #pragma unroll
    for (int r = 0; r < 4; ++r){
      pLds1[q4 * 4 + r][g * 32 + cr]      = acc0[r];
      pLds1[q4 * 4 + r][g * 32 + 16 + cr] = acc1[r];
    }
  }
  __syncthreads();

  // fused LSTM cell update: 512 (row, hidden) units, 1 per thread
  {
    float fp = pLds0[crow][cnn]      + pLds1[crow][cnn];
    float ip = pLds0[crow][32 + cnn] + pLds1[crow][32 + cnn];
    float gp = pLds0[crow][64 + cnn] + pLds1[crow][64 + cnn];
    float op = pLds0[crow][96 + cnn] + pLds1[crow][96 + cnn];
    float fs = sigm(fp);
    float is = sigm(ip);
    float gs = tanh_fast(gp);
    float os = sigm(op);
    float cn = gs * is + cprev * fs;
    cbuf[gi] = cn;
    hout[gi] = f2bf(tanh_fast(cn) * os);
  }
}

// ---- out[b][c] = h_T[b] . Wph[:,c] + bp[c] ---------------------------------
__global__ void final_proj(const u16* __restrict__ h, const float* __restrict__ Wph,
                           const float* __restrict__ bp, float* __restrict__ out){
  __shared__ float red[10][256];
  int b = blockIdx.x, tid = threadIdx.x;
  float p[10];
  #pragma unroll
  for (int c = 0; c < 10; ++c) p[c] = 0.f;
  for (int k = tid; k < HH; k += 256){
    float hv = bf2f(h[b * HH + k]);
    const float* wr = Wph + (size_t)k * 10;
    #pragma unroll
    for (int c = 0; c < 10; ++c) p[c] += hv * wr[c];
  }
  #pragma unroll
  for (int c = 0; c < 10; ++c) red[c][tid] = p[c];
  __syncthreads();
  for (int s = 128; s > 0; s >>= 1){
    if (tid < s){
      #pragma unroll
      for (int c = 0; c < 10; ++c) red[c][tid] += red[c][tid + s];
    }
    __syncthreads();
  }
  if (tid < 10) out[b * 10 + tid] = red[tid][0] + bp[tid];
}

extern "C" void kernel_launch(void* const* d_in, const int* in_sizes, int n_in,
                              void* d_out, int out_size, void* d_ws, size_t ws_size,
                              hipStream_t stream){
  (void)in_sizes; (void)n_in; (void)out_size; (void)ws_size;
  const float* x   = (const float*)d_in[0];
  const float* Wfx = (const float*)d_in[1];
  const float* Wix = (const float*)d_in[2];
  const float* Wgx = (const float*)d_in[3];
  const float* Wox = (const float*)d_in[4];
  const float* Wfh = (const float*)d_in[5];
  const float* Wih = (const float*)d_in[6];
  const float* Wgh = (const float*)d_in[7];
  const float* Woh = (const float*)d_in[8];
  const float* bfv = (const float*)d_in[9];
  const float* biv = (const float*)d_in[10];
  const float* bgv = (const float*)d_in[11];
  const float* bov = (const float*)d_in[12];
  const float* Wph = (const float*)d_in[13];
  const float* bp  = (const float*)d_in[14];

  char* ws = (char*)d_ws;
  u16*  Wpack = (u16*)ws;                    // 10,485,760 B
  u16*  xT    = (u16*)(ws + 10485760);       // 16,777,216 B
  u16*  h0    = (u16*)(ws + 27262976);       //    262,144 B
  u16*  h1    = (u16*)(ws + 27525120);       //    262,144 B
  float* cb   = (float*)(ws + 27787264);     //    524,288 B

  prep_wpack<<<2560, 256, 0, stream>>>(Wfx, Wix, Wgx, Wox, Wfh, Wih, Wgh, Woh, Wpack);
  prep_xT<<<4096, 256, 0, stream>>>(x, xT);
  hipMemsetAsync(h0, 0, 262144, stream);
  hipMemsetAsync(cb, 0, 524288, stream);

  for (int t = 0; t < TT; ++t){
    const u16* hin  = (t & 1) ? h1 : h0;
    u16*       hout = (t & 1) ? h0 : h1;
    lstm_step<<<dim3(32, 8), 512, 0, stream>>>(xT + (size_t)t * BB * DD, Wpack,
                                               hin, hout, cb, bfv, biv, bgv, bov);
  }
  // t=255 (odd) wrote h0 -> final hidden state lives in h0
  final_proj<<<128, 256, 0, stream>>>(h0, Wph, bp, (float*)d_out);
}

// Round 13
// 1757.159 us; speedup vs baseline: 1.3434x; 1.0845x over previous
//
#include <hip/hip_runtime.h>
#include <math.h>

// LSTM: B=128, T=256, D=256, H=1024, C=10
// Round 14: intra-step TLP — 1024-thread blocks, 4-way K-split.
//   R13 (1906us, best) showed the critical path is the serial phase chain
//   (stage -> K-loop -> combine -> cell), not a pipe. Last untried axis:
//   waves/SIMD. This round: 16 waves = 4 gates x 4 K-quarters (10 kt each).
//   - staging 5 -> 2.5 rounds/thread (iter2 guarded tid<512);
//   - 4 waves/SIMD hide L2/MALL latency in every phase (was 2);
//   - per-wave MFMA chain halves (10 iters); prologue B-load MLP doubles.
//   - combine = R13's proven single-phase scheme generalized to 4 partial
//     LDS arrays (kq0 adds bias), still exactly TWO barriers per step.
//   - cell update tid<512, same proven mapping; c-prefetch guarded.
//   VGPR: PFA=3/PFB=4 -> demand ~110 < 128 cap (launch_bounds(1024,1)).
//   LDS: 40KB A + 4x8.45KB partials = 73.8KB, 1 block/CU, grid (32,8).
//   All proven elements bit-identical: A layout + swzb swizzle, staging
//   address formula, C/D mapping, fast-math, c-prefetch, Wpack layout.
// Workspace layout (28,311,552 B total):
//   [0)          Wpack  bf16  10,485,760 B
//   [10485760)   xT     bf16  16,777,216 B   ([T][B][D], x transposed+cast)
//   [27262976)   h0     bf16     262,144 B
//   [27525120)   h1     bf16     262,144 B
//   [27787264)   c      fp32     524,288 B

#define BB 128
#define TT 256
#define DD 256
#define HH 1024
#define NKT 40   // 1280 / 32 k-tiles
#define KQT 10   // k-tiles per K-quarter wave
#define PFA 3    // A-fragment prefetch depth
#define PFB 4    // B-fragment prefetch depth

typedef __bf16 bf16x8 __attribute__((ext_vector_type(8)));
typedef float  f32x4  __attribute__((ext_vector_type(4)));
typedef unsigned short u16;
typedef u16 u16x8 __attribute__((ext_vector_type(8)));

__device__ __forceinline__ u16 f2bf(float f){
  unsigned u = __builtin_bit_cast(unsigned, f);
  u += 0x7fffu + ((u >> 16) & 1u);            // round-to-nearest-even
  return (u16)(u >> 16);
}
__device__ __forceinline__ float bf2f(u16 b){
  unsigned u = ((unsigned)b) << 16;
  return __builtin_bit_cast(float, u);
}
__device__ __forceinline__ float sigm(float x){
  return 1.f / (1.f + __expf(-x));            // R3/R4/R11-proven numerics
}
__device__ __forceinline__ float tanh_fast(float x){
  return 2.f / (1.f + __expf(-2.f * x)) - 1.f;
}
// As4 slot bits: m=[0:3], q=[4:5], kt=[6:11]. R11-proven involution:
// staging wave's 8 consecutive lanes -> 8 distinct bank groups.
__device__ __forceinline__ int swzb(int slot){
  return slot ^ ((slot >> 6) & 7) ^ (((slot >> 4) & 3) << 1);
}

// ---- pack weights into MFMA B-fragment order -------------------------------
// Wpack[ct][kt][lane][j]: ct in [0,256) covers gate-cols [ct*16, ct*16+16)
// (col = gate*1024 + n); element = W[k = kt*32 + (lane>>4)*8 + j][col = ct*16 + (lane&15)]
__global__ void prep_wpack(const float* __restrict__ Wfx, const float* __restrict__ Wix,
                           const float* __restrict__ Wgx, const float* __restrict__ Wox,
                           const float* __restrict__ Wfh, const float* __restrict__ Wih,
                           const float* __restrict__ Wgh, const float* __restrict__ Woh,
                           u16* __restrict__ Wpack){
  int id = blockIdx.x * 256 + threadIdx.x;    // [0, 655360)
  int lane = id & 63;
  int kt = (id >> 6) % NKT;
  int ct = id / (64 * NKT);
  int col = ct * 16 + (lane & 15);
  int g = col >> 10, n = col & 1023;
  int kbase = kt * 32 + (lane >> 4) * 8;
  const float* Wx = (g==0) ? Wfx : (g==1) ? Wix : (g==2) ? Wgx : Wox;
  const float* Wh = (g==0) ? Wfh : (g==1) ? Wih : (g==2) ? Wgh : Woh;
  u16x8 v;
  #pragma unroll
  for (int j = 0; j < 8; ++j){
    int k = kbase + j;
    float f = (k < DD) ? Wx[k * HH + n] : Wh[(k - DD) * HH + n];
    v[j] = f2bf(f);
  }
  *(u16x8*)(Wpack + (size_t)id * 8) = v;      // dst index == id (by construction)
}

// ---- transpose+cast x: xT[t][b][d] = bf16(x[b][t][d]) ----------------------
__global__ void prep_xT(const float* __restrict__ x, u16* __restrict__ xT){
  int id = blockIdx.x * 256 + threadIdx.x;    // [0, 1048576), 8 elems each
  int t = id >> 12;
  int b = (id >> 5) & 127;
  int d0 = (id & 31) * 8;
  const float* src = x + ((size_t)b * TT + t) * DD + d0;
  u16x8 v;
  #pragma unroll
  for (int j = 0; j < 8; ++j) v[j] = f2bf(src[j]);
  *(u16x8*)(xT + (size_t)id * 8) = v;
}

// ---- one LSTM time step: GEMM (bf16 MFMA) + gate activations + state update
// Block: 16 rows x 32 cols x 4 gates, 1024 thr. Waves: g = w&3, kq = w>>2.
__global__ __launch_bounds__(1024, 1) void lstm_step(
    const u16* __restrict__ xTt,   // [128][256] bf16 (t-slice of xT)
    const u16* __restrict__ Wpack,
    const u16* __restrict__ hin,   // [128][1024] bf16
    u16* __restrict__ hout,        // [128][1024] bf16
    float* __restrict__ cbuf,      // [128][1024] fp32
    const float* __restrict__ bfv, const float* __restrict__ biv,
    const float* __restrict__ bgv, const float* __restrict__ bov){
  __shared__ u16x8 As4[NKT * 64];     // 40 KB: A tile, fragment order, swizzled
  __shared__ float pLds[4][16][132];  // per-K-quarter partials (33.8 KB)
  const int tid = threadIdx.x;
  const int n0 = blockIdx.x * 32;  // hidden-unit tile
  const int m0 = blockIdx.y * 16;  // batch-row tile

  // cell-update ownership fixed by tid (tid<512) -> prefetch c-state NOW
  const int crow = tid >> 5, cnn = tid & 31;
  const int gi = (m0 + crow) * HH + n0 + cnn;
  float cprev = 0.f;
  if (tid < 512) cprev = cbuf[gi];

  const int w = tid >> 6, lane = tid & 63, cr = lane & 15, q4 = lane >> 4;
  const int g  = w & 3;            // gate
  const int kq = w >> 2;           // K-quarter: kt in [kq*10, kq*10+10)
  const int ktBeg = kq * KQT;

  // B fragment pointers (global, L2-resident pack); prologue loads issued
  // BEFORE staging so weight latency overlaps the A-staging phase.
  const size_t ct0 = (size_t)(g * 64 + blockIdx.x * 2);  // 2 col-tiles of gate g
  const u16x8* Wp = (const u16x8*)Wpack;
  const u16x8* wq0 = Wp + ct0 * NKT * 64 + lane;
  const u16x8* wq1 = wq0 + NKT * 64;

  u16x8 aP[PFA], b0P[PFB], b1P[PFB];
  #pragma unroll
  for (int i = 0; i < PFB; ++i){
    b0P[i] = wq0[(size_t)(ktBeg + i) * 64];
    b1P[i] = wq1[(size_t)(ktBeg + i) * 64];
  }

  // Stage A = [x_t rows | h rows]: 2560 chunks, 1024 thr -> 2.5 rounds.
  // chunk ch -> row m = ch/160, k0 = (ch%160)*8 ; slot = kt*64 + 16*q + m
  #pragma unroll
  for (int it = 0; it < 3; ++it){
    int ch = tid + it * 1024;
    if (it == 2 && tid >= 512) break;          // 2560 chunks total
    int m = ch / 160;
    int k0 = (ch - m * 160) * 8;
    const u16* src = (k0 < DD) ? (xTt + (m0 + m) * DD + k0)
                               : (hin + (m0 + m) * HH + (k0 - DD));
    u16x8 val = *(const u16x8*)src;
    int kt = k0 >> 5, q = (k0 >> 3) & 3;
    As4[swzb(kt * 64 + 16 * q + m)] = val;
  }
  __syncthreads();

  #pragma unroll
  for (int i = 0; i < PFA; ++i) aP[i] = As4[swzb((ktBeg + i) * 64 + lane)];

  f32x4 acc0 = {0.f, 0.f, 0.f, 0.f}, acc1 = {0.f, 0.f, 0.f, 0.f};
  #pragma unroll
  for (int kt = 0; kt < KQT; ++kt){
    u16x8 ac = aP[kt % PFA], b0 = b0P[kt % PFB], b1 = b1P[kt % PFB];
    if (kt + PFA < KQT)
      aP[kt % PFA] = As4[swzb((ktBeg + kt + PFA) * 64 + lane)];
    if (kt + PFB < KQT){
      b0P[kt % PFB] = wq0[(size_t)(ktBeg + kt + PFB) * 64];
      b1P[kt % PFB] = wq1[(size_t)(ktBeg + kt + PFB) * 64];
    }
    acc0 = __builtin_amdgcn_mfma_f32_16x16x32_bf16(__builtin_bit_cast(bf16x8, ac),
             __builtin_bit_cast(bf16x8, b0), acc0, 0, 0, 0);
    acc1 = __builtin_amdgcn_mfma_f32_16x16x32_bf16(__builtin_bit_cast(bf16x8, ac),
             __builtin_bit_cast(bf16x8, b1), acc1, 0, 0, 0);
  }

  // single-phase combine (R13-proven, generalized to 4 partials):
  // kq=0 writes acc+bias, kq=1..3 write raw acc; ONE barrier.
  // C/D layout: col = cr, row = q4*4 + r.
  if (kq == 0){
    const float* bptr = (g==0) ? bfv : (g==1) ? biv : (g==2) ? bgv : bov;
    const float bias0 = bptr[n0 + cr], bias1 = bptr[n0 + 16 + cr];
    #pragma unroll
    for (int r = 0; r < 4; ++r){
      pLds[0][q4 * 4 + r][g * 32 + cr]      = acc0[r] + bias0;
      pLds[0][q4 * 4 + r][g * 32 + 16 + cr] = acc1[r] + bias1;
    }
  } else {
    #pragma unroll
    for (int r = 0; r < 4; ++r){
      pLds[kq][q4 * 4 + r][g * 32 + cr]      = acc0[r];
      pLds[kq][q4 * 4 + r][g * 32 + 16 + cr] = acc1[r];
    }
  }
  __syncthreads();

  // fused LSTM cell update: 512 (row, hidden) units, tid<512
  if (tid < 512){
    float fp = pLds[0][crow][cnn]      + pLds[1][crow][cnn]
             + pLds[2][crow][cnn]      + pLds[3][crow][cnn];
    float ip = pLds[0][crow][32 + cnn] + pLds[1][crow][32 + cnn]
             + pLds[2][crow][32 + cnn] + pLds[3][crow][32 + cnn];
    float gp = pLds[0][crow][64 + cnn] + pLds[1][crow][64 + cnn]
             + pLds[2][crow][64 + cnn] + pLds[3][crow][64 + cnn];
    float op = pLds[0][crow][96 + cnn] + pLds[1][crow][96 + cnn]
             + pLds[2][crow][96 + cnn] + pLds[3][crow][96 + cnn];
    float fs = sigm(fp);
    float is = sigm(ip);
    float gs = tanh_fast(gp);
    float os = sigm(op);
    float cn = gs * is + cprev * fs;
    cbuf[gi] = cn;
    hout[gi] = f2bf(tanh_fast(cn) * os);
  }
}

// ---- out[b][c] = h_T[b] . Wph[:,c] + bp[c] ---------------------------------
__global__ void final_proj(const u16* __restrict__ h, const float* __restrict__ Wph,
                           const float* __restrict__ bp, float* __restrict__ out){
  __shared__ float red[10][256];
  int b = blockIdx.x, tid = threadIdx.x;
  float p[10];
  #pragma unroll
  for (int c = 0; c < 10; ++c) p[c] = 0.f;
  for (int k = tid; k < HH; k += 256){
    float hv = bf2f(h[b * HH + k]);
    const float* wr = Wph + (size_t)k * 10;
    #pragma unroll
    for (int c = 0; c < 10; ++c) p[c] += hv * wr[c];
  }
  #pragma unroll
  for (int c = 0; c < 10; ++c) red[c][tid] = p[c];
  __syncthreads();
  for (int s = 128; s > 0; s >>= 1){
    if (tid < s){
      #pragma unroll
      for (int c = 0; c < 10; ++c) red[c][tid] += red[c][tid + s];
    }
    __syncthreads();
  }
  if (tid < 10) out[b * 10 + tid] = red[tid][0] + bp[tid];
}

extern "C" void kernel_launch(void* const* d_in, const int* in_sizes, int n_in,
                              void* d_out, int out_size, void* d_ws, size_t ws_size,
                              hipStream_t stream){
  (void)in_sizes; (void)n_in; (void)out_size; (void)ws_size;
  const float* x   = (const float*)d_in[0];
  const float* Wfx = (const float*)d_in[1];
  const float* Wix = (const float*)d_in[2];
  const float* Wgx = (const float*)d_in[3];
  const float* Wox = (const float*)d_in[4];
  const float* Wfh = (const float*)d_in[5];
  const float* Wih = (const float*)d_in[6];
  const float* Wgh = (const float*)d_in[7];
  const float* Woh = (const float*)d_in[8];
  const float* bfv = (const float*)d_in[9];
  const float* biv = (const float*)d_in[10];
  const float* bgv = (const float*)d_in[11];
  const float* bov = (const float*)d_in[12];
  const float* Wph = (const float*)d_in[13];
  const float* bp  = (const float*)d_in[14];

  char* ws = (char*)d_ws;
  u16*  Wpack = (u16*)ws;                    // 10,485,760 B
  u16*  xT    = (u16*)(ws + 10485760);       // 16,777,216 B
  u16*  h0    = (u16*)(ws + 27262976);       //    262,144 B
  u16*  h1    = (u16*)(ws + 27525120);       //    262,144 B
  float* cb   = (float*)(ws + 27787264);     //    524,288 B

  prep_wpack<<<2560, 256, 0, stream>>>(Wfx, Wix, Wgx, Wox, Wfh, Wih, Wgh, Woh, Wpack);
  prep_xT<<<4096, 256, 0, stream>>>(x, xT);
  hipMemsetAsync(h0, 0, 262144, stream);
  hipMemsetAsync(cb, 0, 524288, stream);

  for (int t = 0; t < TT; ++t){
    const u16* hin  = (t & 1) ? h1 : h0;
    u16*       hout = (t & 1) ? h0 : h1;
    lstm_step<<<dim3(32, 8), 1024, 0, stream>>>(xT + (size_t)t * BB * DD, Wpack,
                                                hin, hout, cb, bfv, biv, bgv, bov);
  }
  // t=255 (odd) wrote h0 -> final hidden state lives in h0
  final_proj<<<128, 256, 0, stream>>>(h0, Wph, bp, (float*)d_out);
}